// Round 18
// baseline (400.204 us; speedup 1.0000x reference)
//
#include <hip/hip_runtime.h>
#include <hip/hip_bf16.h>
#include <math.h>

#define B_ 8
#define NQ_ 1024
#define NK_ 1024
#define H_ 8
#define DK_ 64
#define HDK_ 512
#define LOG2E 1.4426950408889634f

typedef _Float16 half8 __attribute__((ext_vector_type(8)));
typedef _Float16 half4 __attribute__((ext_vector_type(4)));
typedef float f32x4 __attribute__((ext_vector_type(4)));

// ---------------------------------------------------------------------------
// Transpose+cast 512x512 weight matrices via LDS tiles: Wt[n][k] = W[k][n].
// Extra block column (x==64, y==0) runs the mask-format detection.
__global__ __launch_bounds__(256)
void wtrans_kernel(const float* __restrict__ w0, const float* __restrict__ w1,
                   const float* __restrict__ w2, const float* __restrict__ w3,
                   _Float16* __restrict__ t0, _Float16* __restrict__ t1,
                   _Float16* __restrict__ t2, _Float16* __restrict__ t3,
                   const unsigned int* __restrict__ maskw, int nwords,
                   int* __restrict__ flag) {
  __shared__ float tile[64][65];
  if (blockIdx.x == 64) {  // detect branch
    if (blockIdx.y != 0) return;
    __shared__ int s;
    if (threadIdx.x == 0) s = 0;
    __syncthreads();
    int bad = 0;
    for (int i = threadIdx.x; i < nwords; i += blockDim.x) {
      unsigned int v = maskw[i];
      if (v > 1u && v != 0x3F800000u) bad = 1;
    }
    if (bad) atomicOr(&s, 1);
    __syncthreads();
    if (threadIdx.x == 0) *flag = s;  // 1 => bytes, 0 => 4-byte words
    return;
  }
  const float* W;
  _Float16* T;
  switch (blockIdx.y) {
    case 0: W = w0; T = t0; break;
    case 1: W = w1; T = t1; break;
    case 2: W = w2; T = t2; break;
    default: W = w3; T = t3; break;
  }
  const int t = blockIdx.x;              // 64 tiles
  const int k0 = (t >> 3) * 64, n0 = (t & 7) * 64;
  const int tid = threadIdx.x;
  const int r = tid >> 4, c4 = (tid & 15) * 4;
#pragma unroll
  for (int i = 0; i < 4; ++i) {
    const int kk = r + i * 16;
    float4 v = *(const float4*)(W + (size_t)(k0 + kk) * 512 + n0 + c4);
    tile[kk][c4 + 0] = v.x;
    tile[kk][c4 + 1] = v.y;
    tile[kk][c4 + 2] = v.z;
    tile[kk][c4 + 3] = v.w;
  }
  __syncthreads();
#pragma unroll
  for (int i = 0; i < 4; ++i) {
    const int nn = r + i * 16;
    half4 h;
#pragma unroll
    for (int j = 0; j < 4; ++j) h[j] = (_Float16)tile[c4 + j][nn];
    *(half4*)(T + (size_t)(n0 + nn) * 512 + k0 + c4) = h;
  }
}

// ---------------------------------------------------------------------------
// 8192x512x512 fp16 MFMA GEMM. mode = mode_base + blockIdx.z:
// mode 0/1/2: Q/K/V projection epilogues (fused in ONE launch, z=3).
// mode 3: output projection (A16 input, f32 output).
__global__ __launch_bounds__(256)
void gemm_kernel(const float* __restrict__ A0, const float* __restrict__ A1,
                 const float* __restrict__ A2, const _Float16* __restrict__ A16,
                 const _Float16* __restrict__ B0, const _Float16* __restrict__ B1,
                 const _Float16* __restrict__ B2, const float* __restrict__ bias0,
                 const float* __restrict__ bias1, const float* __restrict__ bias2,
                 const float* __restrict__ mem, const float* __restrict__ Wmm,
                 const float* __restrict__ bmm, void* __restrict__ out0,
                 void* __restrict__ out1, void* __restrict__ out2,
                 const int mode_base) {
  __shared__ _Float16 As[128 * 32];
  __shared__ _Float16 Bs[128 * 32];
  const int mode = mode_base + blockIdx.z;
  const float* A32 = (mode == 1) ? A1 : (mode == 2) ? A2 : A0;
  const _Float16* Bt = (mode == 1) ? B1 : (mode == 2) ? B2 : B0;
  const float* bias = (mode == 1) ? bias1 : (mode == 2) ? bias2 : bias0;
  void* outp = (mode == 1) ? out1 : (mode == 2) ? out2 : out0;

  const int tid = threadIdx.x;
  const int lane = tid & 63, wave = tid >> 6;
  const int wr = wave >> 1, wc = wave & 1;
  const int l15 = lane & 15, l4 = lane >> 4;
  const int row0 = blockIdx.x * 128, col0 = blockIdx.y * 128;
  const int srow = tid >> 1;
  const int sc0 = (tid & 1) * 2;

  f32x4 acc[4][4] = {};

  for (int k0 = 0; k0 < 512; k0 += 32) {
    __syncthreads();
    const _Float16* sb = Bt + (size_t)(col0 + srow) * 512 + k0;
#pragma unroll
    for (int c = 0; c < 2; ++c) {
      int ci = sc0 + c;
      half8 ha;
      if (mode == 3) {
        ha = *(const half8*)(A16 + (size_t)(row0 + srow) * 512 + k0 + ci * 8);
      } else {
        const float* s = A32 + (size_t)(row0 + srow) * 512 + k0 + ci * 8;
        float4 x = *(const float4*)s;
        float4 y = *(const float4*)(s + 4);
        ha[0] = (_Float16)x.x; ha[1] = (_Float16)x.y;
        ha[2] = (_Float16)x.z; ha[3] = (_Float16)x.w;
        ha[4] = (_Float16)y.x; ha[5] = (_Float16)y.y;
        ha[6] = (_Float16)y.z; ha[7] = (_Float16)y.w;
      }
      float4 vb = *(const float4*)(sb + ci * 8);
      int cd = ci ^ (srow & 3);
      *(half8*)((char*)As + srow * 64 + (cd << 4)) = ha;
      *(float4*)((char*)Bs + srow * 64 + (cd << 4)) = vb;
    }
    __syncthreads();
    half8 af[4], bf[4];
#pragma unroll
    for (int mi = 0; mi < 4; ++mi) {
      int r = wr * 64 + mi * 16 + l15;
      af[mi] = *(half8*)((char*)As + r * 64 + ((l4 ^ (r & 3)) << 4));
    }
#pragma unroll
    for (int ni = 0; ni < 4; ++ni) {
      int r = wc * 64 + ni * 16 + l15;
      bf[ni] = *(half8*)((char*)Bs + r * 64 + ((l4 ^ (r & 3)) << 4));
    }
#pragma unroll
    for (int mi = 0; mi < 4; ++mi)
#pragma unroll
      for (int ni = 0; ni < 4; ++ni)
        acc[mi][ni] =
            __builtin_amdgcn_mfma_f32_16x16x32_f16(af[mi], bf[ni], acc[mi][ni], 0, 0, 0);
  }

#pragma unroll
  for (int mi = 0; mi < 4; ++mi) {
#pragma unroll
    for (int ni = 0; ni < 4; ++ni) {
      const int gc = col0 + wc * 64 + ni * 16 + l15;
      const float bi = bias[gc];
      const int h = gc >> 6, d = gc & 63;
#pragma unroll
      for (int reg = 0; reg < 4; ++reg) {
        const int gr = row0 + wr * 64 + mi * 16 + l4 * 4 + reg;
        float val = acc[mi][ni][reg] + bi;
        if (mode == 3) {
          ((float*)outp)[(size_t)gr * 512 + gc] = val;
        } else if (mode == 0) {
          const int b = gr >> 10, n = gr & 1023;
          ((_Float16*)outp)[((size_t)(b * 8 + h) * 1024 + n) * 64 + d] =
              (_Float16)(val * (LOG2E / 8.0f));
        } else {
          const int b = gr >> 10, n = gr & 1023;
          float mmv = fmaf(mem[gr], Wmm[gc], bmm[gc]);
          float g = val * mmv;
          if (mode == 1)
            ((_Float16*)outp)[((size_t)(b * 8 + h) * 1024 + n) * 64 + d] = (_Float16)g;
          else
            ((_Float16*)outp)[((size_t)(b * 8 + h) * 64 + d) * 1024 + n] = (_Float16)g;
        }
      }
    }
  }
}

// ---------------------------------------------------------------------------
// Flash attention: FULLY-UNROLLED 16-iteration k-loop (no back-edge -> exact
// static waitcnt analysis), ZERO barriers, wave-private K/V tiles staged via
// global_load_lds, explicit hand-counted vmcnt waits. Steady-state FIFO:
// [K=8 | wg=12 | V=8] = 28 outstanding; waits vmcnt(20)/vmcnt(16)/vmcnt(20)
// each give ~1 iteration of latency cover; refills issue right after the
// matching lgkmcnt(0). P tile rows are 144 B (128 B data for KVBLK=64 + 16 B
// pad -- r17's 80 B stride overflowed rows = the correctness bug).
// Softmax: p = g*exp2(s*w - m), m = max(s*w); O^T accumulation keeps rescale
// and l lane-local.
__global__ __launch_bounds__(256, 2)
void attn_kernel(const _Float16* __restrict__ Qp, const _Float16* __restrict__ Kg,
                 const _Float16* __restrict__ Vgt, const float* __restrict__ attw,
                 const float* __restrict__ geom, const void* __restrict__ maskp,
                 const int* __restrict__ flagp, _Float16* __restrict__ Ocat) {
  __shared__ char Kw[4][64 * 128];  // per-wave K [k=64][128B], XOR swizzled
  __shared__ char Vw[4][64 * 128];  // per-wave V^T [d=64][128B], XOR swizzled
  __shared__ char Pw[4][16 * 144];  // per-wave P [q=16][128B data + 16B pad]

  const int tid = threadIdx.x;
  const int lane = tid & 63, wave = tid >> 6;
  const int l15 = lane & 15, l4 = lane >> 4;
  // XCD pinning: bid%8 = h -> one head's K/V on one XCD's L2
  const int bid = blockIdx.x;
  const int qt = bid >> 6;
  const int g = bid & 63;
  const int h = g & 7, b = g >> 3;
  const int bh = b * H_ + h;
  const int qb = qt * 64 + wave * 16;
  const int kq = qb + l15;  // this lane's q row
  const int maskBytes = *flagp;
  const unsigned char* m8 = (const unsigned char*)maskp;
  const int* m32 = (const int*)maskp;

  // Q as B-operand: B[col=l15=q][kk=d]
  half8 aq[2];
  {
    const _Float16* qsrc = Qp + ((size_t)bh * NQ_ + kq) * DK_;
#pragma unroll
    for (int s = 0; s < 2; ++s) aq[s] = *(const half8*)(qsrc + s * 32 + l4 * 8);
  }

  f32x4 fo[4] = {};  // O^T accum: d = c*16 + l4*4 + reg, col q = l15
  float mrun = -INFINITY, lrun = 0.f;

  const char* Kbase = (const char*)(Kg + (size_t)bh * NK_ * DK_);
  const char* Vbase = (const char*)(Vgt + (size_t)bh * DK_ * NK_);
  const size_t wgBase = ((size_t)bh << 20) + (size_t)kq * NK_ + l4 * 4;

  char* const KwB = &Kw[wave][0];
  char* const VwB = &Vw[wave][0];
  char* const PwB = &Pw[wave][0];

  const int srow8 = lane >> 3;  // sub-row within 8-row issue
  const int sc8 = lane & 7;     // 16B chunk

  // ---- K stage: 8 KB = 8 gload_lds (1 KB each), pre-swizzled source
  auto stageK = [&](int kt) {
    const char* kgb = Kbase + (size_t)(kt * 64) * 128;
#pragma unroll
    for (int i = 0; i < 8; ++i) {
      const int r = i * 8 + srow8;
      const char* src = kgb + (size_t)r * 128 + ((sc8 ^ (r & 7)) << 4);
      __builtin_amdgcn_global_load_lds(src, KwB + i * 1024, 16, 0, 0);
    }
  };
  // ---- V stage: 8 KB = 8 gload_lds; V^T global row stride = NK*2 bytes
  auto stageV = [&](int kt) {
    const char* vgb = Vbase + (size_t)kt * 128;
#pragma unroll
    for (int i = 0; i < 8; ++i) {
      const int r = i * 8 + srow8;
      const char* src = vgb + (size_t)r * (NK_ * 2) + ((sc8 ^ (r & 7)) << 4);
      __builtin_amdgcn_global_load_lds(src, VwB + i * 1024, 16, 0, 0);
    }
  };

  // ---- w/g/mask: 12 vmem, ~33 regs (k = c*16 + l4*4 + reg, c = 0..3)
  float4 wv[4], gv[4];
  unsigned mk;
  auto loadWG = [&](int kt) {
    const size_t base = wgBase + (size_t)kt * 64;
    unsigned m = 0;
#pragma unroll
    for (int c = 0; c < 4; ++c) {
      wv[c] = *(const float4*)(attw + base + c * 16);
      gv[c] = *(const float4*)(geom + base + c * 16);
      if (maskBytes) {
        unsigned v = *(const unsigned*)(m8 + base + c * 16);
        m |= (((v & 0xffu) ? 1u : 0u) | ((v & 0xff00u) ? 2u : 0u) |
              ((v & 0xff0000u) ? 4u : 0u) | ((v & 0xff000000u) ? 8u : 0u)) << (c * 4);
      } else {
        int4 v = *(const int4*)(m32 + base + c * 16);
        m |= ((v.x ? 1u : 0u) | (v.y ? 2u : 0u) | (v.z ? 4u : 0u) | (v.w ? 8u : 0u))
             << (c * 4);
      }
    }
    mk = m;
  };

  // prologue: FIFO = [K(0)=8 | wg(0)=12 | V(0)=8]
  stageK(0);
  loadWG(0);
  stageV(0);

#pragma unroll
  for (int kt = 0; kt < 16; ++kt) {
    // ---- wait K(kt) arrived: 20 newer (wg 12 + V 8) stay in flight
    asm volatile("s_waitcnt vmcnt(20)" ::: "memory");
    __builtin_amdgcn_sched_barrier(0);

    // ---- QK^T: A = K rows (private LDS), B = Q; D[k][q]
    f32x4 sf[4];
    __builtin_amdgcn_s_setprio(1);
#pragma unroll
    for (int c = 0; c < 4; ++c) {
      sf[c] = (f32x4){0.f, 0.f, 0.f, 0.f};
#pragma unroll
      for (int s = 0; s < 2; ++s) {
        int r = c * 16 + l15;
        half8 ak = *(half8*)(KwB + r * 128 + (((s * 4 + l4) ^ (r & 7)) << 4));
        sf[c] = __builtin_amdgcn_mfma_f32_16x16x32_f16(ak, aq[s], sf[c], 0, 0, 0);
      }
    }
    __builtin_amdgcn_s_setprio(0);

    // ---- K LDS reads complete -> refill K tile for kt+1
    if (kt + 1 < 16) {
      asm volatile("s_waitcnt lgkmcnt(0)" ::: "memory");
      __builtin_amdgcn_sched_barrier(0);
      stageK(kt + 1);
      __builtin_amdgcn_sched_barrier(0);
    }

    // ---- wait wg(kt) arrived (newer: V 8 + K(kt+1) 8 = 16; last iter: 8)
    if (kt + 1 < 16) {
      asm volatile("s_waitcnt vmcnt(16)" ::: "memory");
    } else {
      asm volatile("s_waitcnt vmcnt(8)" ::: "memory");
    }
    __builtin_amdgcn_sched_barrier(0);

    // ---- scores sw = s*w; bound-max m = max(sw) (log2 g <= 0)
    float mx = -INFINITY;
#pragma unroll
    for (int c = 0; c < 4; ++c)
#pragma unroll
      for (int reg = 0; reg < 4; ++reg) {
        float sv = sf[c][reg] * wv[c][reg];
        sf[c][reg] = sv;
        mx = fmaxf(mx, sv);
      }
    mx = fmaxf(mx, __shfl_xor(mx, 16));
    mx = fmaxf(mx, __shfl_xor(mx, 32));
    const float mn = fmaxf(mrun, mx);
    const float sc = (mrun == -INFINITY) ? 0.f : exp2f(mrun - mn);
    mrun = mn;

    float rs = 0.f;
#pragma unroll
    for (int c = 0; c < 4; ++c)
#pragma unroll
      for (int reg = 0; reg < 4; ++reg) {
        float p = fmaxf(gv[c][reg], 1e-6f) * exp2f(sf[c][reg] - mn);
        p = ((mk >> (c * 4 + reg)) & 1u) ? 0.f : p;
        sf[c][reg] = p;
        rs += p;
      }

    // ---- wg regs dead -> refill for kt+1 (12 HBM loads, ~1 iter cover)
    if (kt + 1 < 16) {
      loadWG(kt + 1);
      __builtin_amdgcn_sched_barrier(0);
    }

    // ---- lane-local rescale (O^T col = q = l15)
#pragma unroll
    for (int c = 0; c < 4; ++c)
#pragma unroll
      for (int reg = 0; reg < 4; ++reg) fo[c][reg] *= sc;
    lrun = lrun * sc + rs;

    // ---- P -> private LDS [q=l15][144B rows] (same-wave)
#pragma unroll
    for (int c = 0; c < 4; ++c) {
      half4 hp;
#pragma unroll
      for (int reg = 0; reg < 4; ++reg) hp[reg] = (_Float16)sf[c][reg];
      *(half4*)(PwB + l15 * 144 + c * 32 + l4 * 8) = hp;
    }

    // ---- wait V(kt) arrived (newer: K(kt+1) 8 + wg(kt+1) 12 = 20; last: 0)
    if (kt + 1 < 16) {
      asm volatile("s_waitcnt vmcnt(20)" ::: "memory");
    } else {
      asm volatile("s_waitcnt vmcnt(0)" ::: "memory");
    }
    __builtin_amdgcn_sched_barrier(0);

    // ---- PV: A = V^T rows d (private LDS), B = P row q; D[d][q] = O^T
    __builtin_amdgcn_s_setprio(1);
#pragma unroll
    for (int s4 = 0; s4 < 2; ++s4) {
      half8 pa = *(half8*)(PwB + l15 * 144 + s4 * 64 + l4 * 16);
#pragma unroll
      for (int c = 0; c < 4; ++c) {
        int rd = c * 16 + l15;
        half8 bv = *(half8*)(VwB + rd * 128 + (((s4 * 4 + l4) ^ (rd & 7)) << 4));
        fo[c] = __builtin_amdgcn_mfma_f32_16x16x32_f16(bv, pa, fo[c], 0, 0, 0);
      }
    }
    __builtin_amdgcn_s_setprio(0);

    // ---- V LDS reads complete -> refill V tile for kt+1
    if (kt + 1 < 16) {
      asm volatile("s_waitcnt lgkmcnt(0)" ::: "memory");
      __builtin_amdgcn_sched_barrier(0);
      stageV(kt + 1);
      __builtin_amdgcn_sched_barrier(0);
    }
  }

  // ---- final: reduce per-lane l partials across 4 k-groups; normalize
  float lsum = lrun;
  lsum += __shfl_xor(lsum, 16);
  lsum += __shfl_xor(lsum, 32);
  const float rinv = 1.0f / lsum;

  _Float16* orow = Ocat + ((size_t)b * NQ_ + kq) * HDK_ + h * DK_;
#pragma unroll
  for (int c = 0; c < 4; ++c) {
    half4 hv;
#pragma unroll
    for (int reg = 0; reg < 4; ++reg) hv[reg] = (_Float16)(fo[c][reg] * rinv);
    *(half4*)(orow + c * 16 + l4 * 4) = hv;
  }
}

// ---------------------------------------------------------------------------
extern "C" void kernel_launch(void* const* d_in, const int* in_sizes, int n_in,
                              void* d_out, int out_size, void* d_ws, size_t ws_size,
                              hipStream_t stream) {
  (void)in_sizes; (void)n_in; (void)out_size; (void)ws_size;
  const float* queries = (const float*)d_in[0];
  const float* keys    = (const float*)d_in[1];
  const float* values  = (const float*)d_in[2];
  const void*  maskp   = d_in[3];
  const float* attw    = (const float*)d_in[4];
  const float* memo    = (const float*)d_in[5];
  const float* geom    = (const float*)d_in[6];
  const float* Wq = (const float*)d_in[7];
  const float* bq = (const float*)d_in[8];
  const float* Wk = (const float*)d_in[9];
  const float* bk = (const float*)d_in[10];
  const float* Wv = (const float*)d_in[11];
  const float* bv = (const float*)d_in[12];
  const float* Wmm = (const float*)d_in[13];
  const float* bmm = (const float*)d_in[14];
  const float* Wo = (const float*)d_in[15];
  const float* bo = (const float*)d_in[16];

  char* ws = (char*)d_ws;
  size_t off = 0;
  auto alloc = [&](size_t bytes) {
    char* p = ws + off;
    off += (bytes + 255) & ~(size_t)255;
    return p;
  };
  const size_t MAT = (size_t)8192 * 512 * 2;  // 8 MiB fp16
  int* flag = (int*)alloc(256);
  _Float16* Wtq = (_Float16*)alloc((size_t)512 * 512 * 2);
  _Float16* Wtk = (_Float16*)alloc((size_t)512 * 512 * 2);
  _Float16* Wtv = (_Float16*)alloc((size_t)512 * 512 * 2);
  _Float16* Wto = (_Float16*)alloc((size_t)512 * 512 * 2);
  _Float16* Qp   = (_Float16*)alloc(MAT);
  _Float16* Kgp  = (_Float16*)alloc(MAT);
  _Float16* Vgtp = (_Float16*)alloc(MAT);
  _Float16* Ocat = (_Float16*)alloc(MAT);

  // transpose weights + mask detect in one launch
  wtrans_kernel<<<dim3(65, 4), 256, 0, stream>>>(Wq, Wk, Wv, Wo, Wtq, Wtk, Wtv, Wto,
                                                 (const unsigned int*)maskp, 4096, flag);

  // fused Q/K/V projections: one launch, z selects the projection
  gemm_kernel<<<dim3(64, 4, 3), 256, 0, stream>>>(
      queries, keys, values, nullptr, Wtq, Wtk, Wtv, bq, bk, bv, memo, Wmm, bmm,
      Qp, Kgp, Vgtp, 0);

  attn_kernel<<<1024, 256, 0, stream>>>(Qp, Kgp, Vgtp, attw, geom, maskp, flag, Ocat);

  // output projection (mode 3)
  gemm_kernel<<<dim3(64, 4, 1), 256, 0, stream>>>(
      nullptr, nullptr, nullptr, Ocat, Wto, nullptr, nullptr, bo, nullptr, nullptr,
      nullptr, nullptr, nullptr, d_out, nullptr, nullptr, 3);
}

// Round 19
// 319.822 us; speedup vs baseline: 1.2513x; 1.2513x over previous
//
#include <hip/hip_runtime.h>
#include <hip/hip_bf16.h>
#include <math.h>

#define B_ 8
#define NQ_ 1024
#define NK_ 1024
#define H_ 8
#define DK_ 64
#define HDK_ 512
#define LOG2E 1.4426950408889634f

typedef _Float16 half8 __attribute__((ext_vector_type(8)));
typedef _Float16 half4 __attribute__((ext_vector_type(4)));
typedef float f32x4 __attribute__((ext_vector_type(4)));

// ---------------------------------------------------------------------------
// Transpose+cast 512x512 weight matrices via LDS tiles: Wt[n][k] = W[k][n].
// Extra block column (x==64, y==0) runs the mask-format detection (1-byte vs
// 4-byte elements) so no separate launch is needed.
__global__ __launch_bounds__(256)
void wtrans_kernel(const float* __restrict__ w0, const float* __restrict__ w1,
                   const float* __restrict__ w2, const float* __restrict__ w3,
                   _Float16* __restrict__ t0, _Float16* __restrict__ t1,
                   _Float16* __restrict__ t2, _Float16* __restrict__ t3,
                   const unsigned int* __restrict__ maskw, int nwords,
                   int* __restrict__ flag) {
  __shared__ float tile[64][65];
  if (blockIdx.x == 64) {  // detect branch
    if (blockIdx.y != 0) return;
    __shared__ int s;
    if (threadIdx.x == 0) s = 0;
    __syncthreads();
    int bad = 0;
    for (int i = threadIdx.x; i < nwords; i += blockDim.x) {
      unsigned int v = maskw[i];
      if (v > 1u && v != 0x3F800000u) bad = 1;
    }
    if (bad) atomicOr(&s, 1);
    __syncthreads();
    if (threadIdx.x == 0) *flag = s;  // 1 => bytes, 0 => 4-byte words
    return;
  }
  const float* W;
  _Float16* T;
  switch (blockIdx.y) {
    case 0: W = w0; T = t0; break;
    case 1: W = w1; T = t1; break;
    case 2: W = w2; T = t2; break;
    default: W = w3; T = t3; break;
  }
  const int t = blockIdx.x;              // 64 tiles
  const int k0 = (t >> 3) * 64, n0 = (t & 7) * 64;
  const int tid = threadIdx.x;
  const int r = tid >> 4, c4 = (tid & 15) * 4;
#pragma unroll
  for (int i = 0; i < 4; ++i) {
    const int kk = r + i * 16;
    float4 v = *(const float4*)(W + (size_t)(k0 + kk) * 512 + n0 + c4);
    tile[kk][c4 + 0] = v.x;
    tile[kk][c4 + 1] = v.y;
    tile[kk][c4 + 2] = v.z;
    tile[kk][c4 + 3] = v.w;
  }
  __syncthreads();
#pragma unroll
  for (int i = 0; i < 4; ++i) {
    const int nn = r + i * 16;
    half4 h;
#pragma unroll
    for (int j = 0; j < 4; ++j) h[j] = (_Float16)tile[c4 + j][nn];
    *(half4*)(T + (size_t)(n0 + nn) * 512 + k0 + c4) = h;
  }
}

// ---------------------------------------------------------------------------
// 8192x512x512 fp16 MFMA GEMM. mode = mode_base + blockIdx.z:
// mode 0/1/2: Q/K/V projection epilogues (fused in ONE launch, z=3).
// mode 3: output projection (A16 input, f32 output).
__global__ __launch_bounds__(256)
void gemm_kernel(const float* __restrict__ A0, const float* __restrict__ A1,
                 const float* __restrict__ A2, const _Float16* __restrict__ A16,
                 const _Float16* __restrict__ B0, const _Float16* __restrict__ B1,
                 const _Float16* __restrict__ B2, const float* __restrict__ bias0,
                 const float* __restrict__ bias1, const float* __restrict__ bias2,
                 const float* __restrict__ mem, const float* __restrict__ Wmm,
                 const float* __restrict__ bmm, void* __restrict__ out0,
                 void* __restrict__ out1, void* __restrict__ out2,
                 const int mode_base) {
  __shared__ _Float16 As[128 * 32];
  __shared__ _Float16 Bs[128 * 32];
  const int mode = mode_base + blockIdx.z;
  const float* A32 = (mode == 1) ? A1 : (mode == 2) ? A2 : A0;
  const _Float16* Bt = (mode == 1) ? B1 : (mode == 2) ? B2 : B0;
  const float* bias = (mode == 1) ? bias1 : (mode == 2) ? bias2 : bias0;
  void* outp = (mode == 1) ? out1 : (mode == 2) ? out2 : out0;

  const int tid = threadIdx.x;
  const int lane = tid & 63, wave = tid >> 6;
  const int wr = wave >> 1, wc = wave & 1;
  const int l15 = lane & 15, l4 = lane >> 4;
  const int row0 = blockIdx.x * 128, col0 = blockIdx.y * 128;
  const int srow = tid >> 1;
  const int sc0 = (tid & 1) * 2;

  f32x4 acc[4][4] = {};

  for (int k0 = 0; k0 < 512; k0 += 32) {
    __syncthreads();
    const _Float16* sb = Bt + (size_t)(col0 + srow) * 512 + k0;
#pragma unroll
    for (int c = 0; c < 2; ++c) {
      int ci = sc0 + c;
      half8 ha;
      if (mode == 3) {
        ha = *(const half8*)(A16 + (size_t)(row0 + srow) * 512 + k0 + ci * 8);
      } else {
        const float* s = A32 + (size_t)(row0 + srow) * 512 + k0 + ci * 8;
        float4 x = *(const float4*)s;
        float4 y = *(const float4*)(s + 4);
        ha[0] = (_Float16)x.x; ha[1] = (_Float16)x.y;
        ha[2] = (_Float16)x.z; ha[3] = (_Float16)x.w;
        ha[4] = (_Float16)y.x; ha[5] = (_Float16)y.y;
        ha[6] = (_Float16)y.z; ha[7] = (_Float16)y.w;
      }
      float4 vb = *(const float4*)(sb + ci * 8);
      int cd = ci ^ (srow & 3);
      *(half8*)((char*)As + srow * 64 + (cd << 4)) = ha;
      *(float4*)((char*)Bs + srow * 64 + (cd << 4)) = vb;
    }
    __syncthreads();
    half8 af[4], bf[4];
#pragma unroll
    for (int mi = 0; mi < 4; ++mi) {
      int r = wr * 64 + mi * 16 + l15;
      af[mi] = *(half8*)((char*)As + r * 64 + ((l4 ^ (r & 3)) << 4));
    }
#pragma unroll
    for (int ni = 0; ni < 4; ++ni) {
      int r = wc * 64 + ni * 16 + l15;
      bf[ni] = *(half8*)((char*)Bs + r * 64 + ((l4 ^ (r & 3)) << 4));
    }
#pragma unroll
    for (int mi = 0; mi < 4; ++mi)
#pragma unroll
      for (int ni = 0; ni < 4; ++ni)
        acc[mi][ni] =
            __builtin_amdgcn_mfma_f32_16x16x32_f16(af[mi], bf[ni], acc[mi][ni], 0, 0, 0);
  }

#pragma unroll
  for (int mi = 0; mi < 4; ++mi) {
#pragma unroll
    for (int ni = 0; ni < 4; ++ni) {
      const int gc = col0 + wc * 64 + ni * 16 + l15;
      const float bi = bias[gc];
      const int h = gc >> 6, d = gc & 63;
#pragma unroll
      for (int reg = 0; reg < 4; ++reg) {
        const int gr = row0 + wr * 64 + mi * 16 + l4 * 4 + reg;
        float val = acc[mi][ni][reg] + bi;
        if (mode == 3) {
          ((float*)outp)[(size_t)gr * 512 + gc] = val;
        } else if (mode == 0) {
          const int b = gr >> 10, n = gr & 1023;
          ((_Float16*)outp)[((size_t)(b * 8 + h) * 1024 + n) * 64 + d] =
              (_Float16)(val * (LOG2E / 8.0f));
        } else {
          const int b = gr >> 10, n = gr & 1023;
          float mmv = fmaf(mem[gr], Wmm[gc], bmm[gc]);
          float g = val * mmv;
          if (mode == 1)
            ((_Float16*)outp)[((size_t)(b * 8 + h) * 1024 + n) * 64 + d] = (_Float16)g;
          else
            ((_Float16*)outp)[((size_t)(b * 8 + h) * 64 + d) * 1024 + n] = (_Float16)g;
        }
      }
    }
  }
}

// ---------------------------------------------------------------------------
// Flash attention (round-12 configuration -- best measured: attn ~252 us,
// total 319.9 us). Double-buffered K/V via global_load_lds, one barrier/iter,
// swapped QK^T, no log2 on the critical path (p = g * exp2(s*w - m) with
// m = max(s*w), valid since log2 g <= 0), transposed PV accumulating O^T so
// softmax rescale and l are lane-local.
__global__ __launch_bounds__(256, 2)
void attn_kernel(const _Float16* __restrict__ Qp, const _Float16* __restrict__ Kg,
                 const _Float16* __restrict__ Vgt, const float* __restrict__ attw,
                 const float* __restrict__ geom, const void* __restrict__ maskp,
                 const int* __restrict__ flagp, _Float16* __restrict__ Ocat) {
  __shared__ _Float16 Kbuf[2][64 * 64];  // [k][d], 128B rows, XOR swizzled
  __shared__ _Float16 Vbuf[2][64 * 64];  // [d][k], 128B rows, XOR swizzled
  __shared__ _Float16 Ps[4][16 * 64];    // per-wave P, [q][k], swizzled

  const int tid = threadIdx.x;
  const int lane = tid & 63, wave = tid >> 6;
  const int l15 = lane & 15, l4 = lane >> 4;
  // XCD swizzle: bid&63 = (b,h) -> head pinned to one XCD; K/V L2-resident
  const int bid = blockIdx.x;
  const int qt = bid >> 6;
  const int g = bid & 63;
  const int h = g & 7, b = g >> 3;
  const int bh = b * H_ + h;
  const int qb = qt * 64 + wave * 16;
  const int kq = qb + l15;  // this lane's q row
  const int maskBytes = *flagp;
  const unsigned char* m8 = (const unsigned char*)maskp;
  const int* m32 = (const int*)maskp;

  // Q as B-operand: B[col=l15=q][kk=d]
  half8 aq[2];
  {
    const _Float16* qsrc = Qp + ((size_t)bh * NQ_ + kq) * DK_;
#pragma unroll
    for (int s = 0; s < 2; ++s) aq[s] = *(const half8*)(qsrc + s * 32 + l4 * 8);
  }

  f32x4 fo[4] = {};  // O^T accum: row=d(c*16+l4*4+reg), col=q=l15 (lane-local)
  float mrun = -INFINITY, lrun = 0.f;

  const size_t wgBase = ((size_t)bh << 20) + (size_t)kq * NK_ + l4 * 4;

  // ---- direct global->LDS staging, pre-swizzled source (involution XOR)
  const int srL = lane >> 3;   // sub-row within 8-row issue
  const int sci = lane & 7;    // physical 16B chunk
  auto stageKV = [&](int kt, int sel) {
    const char* kgb = (const char*)(Kg + ((size_t)bh * NK_ + kt * 64) * DK_);
    const char* vgb = (const char*)(Vgt + (size_t)bh * DK_ * NK_ + kt * 64);
#pragma unroll
    for (int i = 0; i < 2; ++i) {
      const int rbase = wave * 16 + i * 8;
      const int r = rbase + srL;
      const char* src = kgb + (size_t)r * 128 + ((sci ^ (r & 7)) << 4);
      __builtin_amdgcn_global_load_lds(src, (char*)&Kbuf[sel][0] + rbase * 128, 16, 0, 0);
    }
#pragma unroll
    for (int i = 0; i < 2; ++i) {
      const int rbase = wave * 16 + i * 8;
      const int r = rbase + srL;
      const char* src = vgb + (size_t)r * (NK_ * 2) + ((sci ^ (r & 7)) << 4);
      __builtin_amdgcn_global_load_lds(src, (char*)&Vbuf[sel][0] + rbase * 128, 16, 0, 0);
    }
  };

  // ---- single w/g/mask register set (mask packed: bit c*4+reg) = 12 vmem
  float4 wv[4], gv[4];
  unsigned mk;
  auto loadWG = [&](int kt) {
    const size_t base = wgBase + (size_t)kt * 64;
    unsigned m = 0;
#pragma unroll
    for (int c = 0; c < 4; ++c) {
      wv[c] = *(const float4*)(attw + base + c * 16);
      gv[c] = *(const float4*)(geom + base + c * 16);
      if (maskBytes) {
        unsigned v = *(const unsigned*)(m8 + base + c * 16);
        m |= (((v & 0xffu) ? 1u : 0u) | ((v & 0xff00u) ? 2u : 0u) |
              ((v & 0xff0000u) ? 4u : 0u) | ((v & 0xff000000u) ? 8u : 0u)) << (c * 4);
      } else {
        int4 v = *(const int4*)(m32 + base + c * 16);
        m |= ((v.x ? 1u : 0u) | (v.y ? 2u : 0u) | (v.z ? 4u : 0u) | (v.w ? 8u : 0u))
             << (c * 4);
      }
    }
    mk = m;
  };

  // prologue: stage tile 0, load wg 0, drain, barrier
  stageKV(0, 0);
  loadWG(0);
  __syncthreads();

#pragma unroll 2
  for (int kt = 0; kt < 16; ++kt) {
    const int sel = kt & 1;
    if (kt + 1 < 16) stageKV(kt + 1, sel ^ 1);  // async, drained at barrier

    const char* Kb = (const char*)&Kbuf[sel][0];
    const char* Vb = (const char*)&Vbuf[sel][0];

    // ---- QK^T swapped: A = K rows (k), B = Q cols (q); D[k][q]
    f32x4 sf[4];
    __builtin_amdgcn_s_setprio(1);
#pragma unroll
    for (int c = 0; c < 4; ++c) {
      sf[c] = (f32x4){0.f, 0.f, 0.f, 0.f};
#pragma unroll
      for (int s = 0; s < 2; ++s) {
        int r = c * 16 + l15;
        half8 ak = *(half8*)(Kb + r * 128 + (((s * 4 + l4) ^ (r & 7)) << 4));
        sf[c] = __builtin_amdgcn_mfma_f32_16x16x32_f16(ak, aq[s], sf[c], 0, 0, 0);
      }
    }
    __builtin_amdgcn_s_setprio(0);

    // ---- weighted scores sw = s*w; bound-max m = max(sw) (log2 g <= 0)
    float mx = -INFINITY;
#pragma unroll
    for (int c = 0; c < 4; ++c)
#pragma unroll
      for (int reg = 0; reg < 4; ++reg) {
        float sv = sf[c][reg] * wv[c][reg];
        sf[c][reg] = sv;
        mx = fmaxf(mx, sv);
      }
    mx = fmaxf(mx, __shfl_xor(mx, 16));
    mx = fmaxf(mx, __shfl_xor(mx, 32));
    const float mn = fmaxf(mrun, mx);
    const float sc = (mrun == -INFINITY) ? 0.f : exp2f(mrun - mn);
    mrun = mn;

    // ---- p = g * exp2(sw - mn), masked -> 0  (no log2 anywhere)
    float rs = 0.f;
#pragma unroll
    for (int c = 0; c < 4; ++c)
#pragma unroll
      for (int reg = 0; reg < 4; ++reg) {
        float p = fmaxf(gv[c][reg], 1e-6f) * exp2f(sf[c][reg] - mn);
        p = ((mk >> (c * 4 + reg)) & 1u) ? 0.f : p;
        sf[c][reg] = p;
        rs += p;
      }

    // wg registers now dead -> issue next tile's 12 stream loads into them
    if (kt + 1 < 16) loadWG(kt + 1);

    // ---- lane-local rescale (O^T col = q = l15 = this lane's softmax row)
#pragma unroll
    for (int c = 0; c < 4; ++c)
#pragma unroll
      for (int reg = 0; reg < 4; ++reg) fo[c][reg] *= sc;
    lrun = lrun * sc + rs;  // per-lane partial sum (consistent scale)

    // ---- P -> per-wave LDS [q=l15][k], swizzled (same-wave, no barrier)
    char* pw = (char*)&Ps[wave][0];
#pragma unroll
    for (int c = 0; c < 4; ++c) {
      half4 hp;
#pragma unroll
      for (int reg = 0; reg < 4; ++reg) hp[reg] = (_Float16)sf[c][reg];
      int ci = c * 2 + (l4 >> 1);
      *(half4*)(pw + l15 * 128 + ((ci ^ (l15 & 7)) << 4) + (l4 & 1) * 8) = hp;
    }

    // ---- PV transposed: A = Vs rows (d), B = P rows (q); D[d][q] = O^T
    __builtin_amdgcn_s_setprio(1);
#pragma unroll
    for (int s4 = 0; s4 < 2; ++s4) {
      half8 pa = *(half8*)(pw + l15 * 128 + (((s4 * 4 + l4) ^ (l15 & 7)) << 4));
#pragma unroll
      for (int c = 0; c < 4; ++c) {
        int rd = c * 16 + l15;
        half8 bv = *(half8*)(Vb + rd * 128 + (((s4 * 4 + l4) ^ (rd & 7)) << 4));
        fo[c] = __builtin_amdgcn_mfma_f32_16x16x32_f16(bv, pa, fo[c], 0, 0, 0);
      }
    }
    __builtin_amdgcn_s_setprio(0);

    __syncthreads();  // drains stage(kt+1); flips buffers
  }

  // ---- final: reduce per-lane l partials across 4 k-groups; normalize
  float lsum = lrun;
  lsum += __shfl_xor(lsum, 16);
  lsum += __shfl_xor(lsum, 32);
  const float rinv = 1.0f / lsum;

  _Float16* orow = Ocat + ((size_t)b * NQ_ + kq) * HDK_ + h * DK_;
#pragma unroll
  for (int c = 0; c < 4; ++c) {
    half4 hv;
#pragma unroll
    for (int reg = 0; reg < 4; ++reg) hv[reg] = (_Float16)(fo[c][reg] * rinv);
    *(half4*)(orow + c * 16 + l4 * 4) = hv;
  }
}

// ---------------------------------------------------------------------------
extern "C" void kernel_launch(void* const* d_in, const int* in_sizes, int n_in,
                              void* d_out, int out_size, void* d_ws, size_t ws_size,
                              hipStream_t stream) {
  (void)in_sizes; (void)n_in; (void)out_size; (void)ws_size;
  const float* queries = (const float*)d_in[0];
  const float* keys    = (const float*)d_in[1];
  const float* values  = (const float*)d_in[2];
  const void*  maskp   = d_in[3];
  const float* attw    = (const float*)d_in[4];
  const float* memo    = (const float*)d_in[5];
  const float* geom    = (const float*)d_in[6];
  const float* Wq = (const float*)d_in[7];
  const float* bq = (const float*)d_in[8];
  const float* Wk = (const float*)d_in[9];
  const float* bk = (const float*)d_in[10];
  const float* Wv = (const float*)d_in[11];
  const float* bv = (const float*)d_in[12];
  const float* Wmm = (const float*)d_in[13];
  const float* bmm = (const float*)d_in[14];
  const float* Wo = (const float*)d_in[15];
  const float* bo = (const float*)d_in[16];

  char* ws = (char*)d_ws;
  size_t off = 0;
  auto alloc = [&](size_t bytes) {
    char* p = ws + off;
    off += (bytes + 255) & ~(size_t)255;
    return p;
  };
  const size_t MAT = (size_t)8192 * 512 * 2;  // 8 MiB fp16
  int* flag = (int*)alloc(256);
  _Float16* Wtq = (_Float16*)alloc((size_t)512 * 512 * 2);
  _Float16* Wtk = (_Float16*)alloc((size_t)512 * 512 * 2);
  _Float16* Wtv = (_Float16*)alloc((size_t)512 * 512 * 2);
  _Float16* Wto = (_Float16*)alloc((size_t)512 * 512 * 2);
  _Float16* Qp   = (_Float16*)alloc(MAT);
  _Float16* Kgp  = (_Float16*)alloc(MAT);
  _Float16* Vgtp = (_Float16*)alloc(MAT);
  _Float16* Ocat = (_Float16*)alloc(MAT);

  // transpose weights + mask detect in one launch
  wtrans_kernel<<<dim3(65, 4), 256, 0, stream>>>(Wq, Wk, Wv, Wo, Wtq, Wtk, Wtv, Wto,
                                                 (const unsigned int*)maskp, 4096, flag);

  // fused Q/K/V projections: one launch, z selects the projection
  gemm_kernel<<<dim3(64, 4, 3), 256, 0, stream>>>(
      queries, keys, values, nullptr, Wtq, Wtk, Wtv, bq, bk, bv, memo, Wmm, bmm,
      Qp, Kgp, Vgtp, 0);

  attn_kernel<<<1024, 256, 0, stream>>>(Qp, Kgp, Vgtp, attw, geom, maskp, flag, Ocat);

  // output projection (mode 3)
  gemm_kernel<<<dim3(64, 4, 1), 256, 0, stream>>>(
      nullptr, nullptr, nullptr, Ocat, Wto, nullptr, nullptr, bo, nullptr, nullptr,
      nullptr, nullptr, nullptr, d_out, nullptr, nullptr, 3);
}